// Round 5
// baseline (277.847 us; speedup 1.0000x reference)
//
#include <hip/hip_runtime.h>
#include <hip/hip_bf16.h>
#include <math.h>

#define MAXO 16

// ---------------------------------------------------------------------------
// m1: IoU over (b, d-chunk). Per-default argmax over objects (first-wins) ->
//     tcls/ovl. Per-object argmax over defaults (max iou, lowest d) reduced
//     block-locally and written NON-atomically per chunk to key64c[b][c][o].
//     Also initializes all scalar accumulators (consumed by later kernels).
// ---------------------------------------------------------------------------
__global__ __launch_bounds__(256, 2)
void m1_kernel(const float* __restrict__ boxes,   // [B,O,4] xy
               const float* __restrict__ dboxes,  // [D,4] cxcy
               int*   __restrict__ tcls,          // [B,D] obj idx
               float* __restrict__ ovl,           // [B,D] best iou
               unsigned long long* __restrict__ key64c, // [B,CH,O]
               int*    __restrict__ n_pos,        // [B]
               double* __restrict__ loc_sum,
               double* __restrict__ pos_sum,
               double* __restrict__ neg_sum,
               int*    __restrict__ npt,
               int*    __restrict__ counter,
               int D, int O, int CH, int chunk) {
    int b = blockIdx.x / CH, c = blockIdx.x % CH;
    int t = threadIdx.x;

    // init accumulators (later kernels only; stream-ordered => race-free)
    if (c == 0) {
        if (t == 0) n_pos[b] = 0;
        if (b == 0) {
            if (t == 1) *loc_sum = 0.0;
            if (t == 2) *pos_sum = 0.0;
            if (t == 3) *neg_sum = 0.0;
            if (t == 4) *npt = 0;
            if (t == 5) *counter = 0;
        }
    }

    __shared__ float sbox[MAXO][4];
    __shared__ float sarea[MAXO];
    __shared__ unsigned long long skey[4][MAXO];
    if (t < O) {
        const float* bp = boxes + ((size_t)b * O + t) * 4;
        float x1 = bp[0], y1 = bp[1], x2 = bp[2], y2 = bp[3];
        sbox[t][0] = x1; sbox[t][1] = y1; sbox[t][2] = x2; sbox[t][3] = y2;
        sarea[t] = (x2 - x1) * (y2 - y1);
    }
    __syncthreads();

    unsigned long long bestk[MAXO];
#pragma unroll
    for (int o = 0; o < MAXO; ++o) bestk[o] = 0ull;

    size_t rowoff = (size_t)b * D;
    int d0 = c * chunk, d1 = min(D, d0 + chunk);

    for (int d = d0 + t; d < d1; d += 256) {
        float4 db = ((const float4*)dboxes)[d];
        float dx1 = db.x - db.z * 0.5f, dy1 = db.y - db.w * 0.5f;
        float dx2 = db.x + db.z * 0.5f, dy2 = db.y + db.w * 0.5f;
        float a2 = (dx2 - dx1) * (dy2 - dy1);
        unsigned notd = 0xFFFFFFFFu - (unsigned)d;
        float mval = -1.0f; int mobj = 0;
#pragma unroll
        for (int o = 0; o < MAXO; ++o) {
            if (o < O) {
                float lx = fmaxf(sbox[o][0], dx1), ly = fmaxf(sbox[o][1], dy1);
                float rx = fminf(sbox[o][2], dx2), ry = fminf(sbox[o][3], dy2);
                float w = fmaxf(rx - lx, 0.0f), h = fmaxf(ry - ly, 0.0f);
                float inter = w * h;
                float iou = inter / (sarea[o] + a2 - inter);
                if (iou > mval) { mval = iou; mobj = o; }   // first-wins over o
                unsigned long long key =
                    ((unsigned long long)__float_as_uint(iou) << 32) |
                    (unsigned long long)notd;               // max iou, lowest d
                if (key > bestk[o]) bestk[o] = key;
            }
        }
        tcls[rowoff + d] = mobj;
        ovl[rowoff + d]  = mval;
    }

    int w = t >> 6;
#pragma unroll
    for (int o = 0; o < MAXO; ++o) {
        if (o < O) {
            unsigned long long k = bestk[o];
            for (int s = 32; s > 0; s >>= 1) {
                unsigned long long k2 =
                    (unsigned long long)__shfl_xor((long long)k, s);
                if (k2 > k) k = k2;
            }
            if ((t & 63) == 0) skey[w][o] = k;
        }
    }
    __syncthreads();
    if (t < O) {
        unsigned long long k = skey[0][t];
#pragma unroll
        for (int i = 1; i < 4; ++i) {
            unsigned long long k2 = skey[i][t];
            if (k2 > k) k = k2;
        }
        key64c[((size_t)b * CH + c) * O + t] = k;   // plain store, no atomic
    }
}

// ---------------------------------------------------------------------------
// m2r: reduce key64c over chunks -> dstar[b][o] (tiny)
// ---------------------------------------------------------------------------
__global__ void m2r_kernel(const unsigned long long* __restrict__ key64c,
                           int* __restrict__ dstar, int B, int O, int CH) {
    int n = B * O;
    for (int idx = threadIdx.x; idx < n; idx += blockDim.x) {
        int b = idx / O, o = idx % O;
        unsigned long long k = 0ull;
        for (int c = 0; c < CH; ++c) {
            unsigned long long k2 = key64c[((size_t)b * CH + c) * O + o];
            if (k2 > k) k = k2;
        }
        dstar[idx] = (int)(0xFFFFFFFFu - (unsigned)(k & 0xFFFFFFFFull));
    }
}

// ---------------------------------------------------------------------------
// m3: label assignment (override applied inline, ascending scan = last-wins),
//     encode + smooth-L1 for positives; n_pos / npt / loc_sum
// ---------------------------------------------------------------------------
__global__ void m3_kernel(const float* __restrict__ boxes,
                          const int*   __restrict__ labels,
                          const float* __restrict__ dboxes,
                          const float* __restrict__ locs,
                          int*   __restrict__ tcls,
                          const float* __restrict__ ovl,
                          const int*   __restrict__ dstar, // [B,O]
                          int*   __restrict__ n_pos,
                          double* __restrict__ loc_sum,
                          int*   __restrict__ npt,
                          int D, int O, int CHm) {
    int b = blockIdx.x / CHm, c = blockIdx.x % CHm;
    int t = threadIdx.x;
    int d = c * 256 + t;

    __shared__ float sbox[MAXO][4];
    __shared__ int   slab[MAXO];
    __shared__ int   sdstar[MAXO];
    __shared__ double sred[256];
    __shared__ int    sredi[256];
    if (t < O) {
        const float* bp = boxes + ((size_t)b * O + t) * 4;
        sbox[t][0] = bp[0]; sbox[t][1] = bp[1]; sbox[t][2] = bp[2]; sbox[t][3] = bp[3];
        slab[t] = labels[(size_t)b * O + t];
        sdstar[t] = dstar[(size_t)b * O + t];
    }
    __syncthreads();

    double acc = 0.0;
    int cnt = 0;
    if (d < D) {
        size_t rowoff = (size_t)b * D;
        int o = tcls[rowoff + d];
        float ov = ovl[rowoff + d];
#pragma unroll
        for (int oo = 0; oo < MAXO; ++oo) {        // ascending -> last-write-wins
            if (oo < O && sdstar[oo] == d) { o = oo; ov = 1.0f; }
        }
        int lab = (ov < 0.5f) ? 0 : slab[o];
        tcls[rowoff + d] = lab;
        if (lab != 0) {
            cnt = 1;
            float x1 = sbox[o][0], y1 = sbox[o][1], x2 = sbox[o][2], y2 = sbox[o][3];
            float cx = (x1 + x2) * 0.5f, cy = (y1 + y2) * 0.5f;
            float w = x2 - x1, h = y2 - y1;
            float4 db = ((const float4*)dboxes)[d];
            float g0 = (cx - db.x) / (db.z * 0.1f);
            float g1 = (cy - db.y) / (db.w * 0.1f);
            float g2 = __logf(w / db.z) * 5.0f;
            float g3 = __logf(h / db.w) * 5.0f;
            float4 lp = ((const float4*)locs)[rowoff + d];
            float dd;
            dd = fabsf(lp.x - g0); acc += (dd < 1.0f) ? 0.5f * dd * dd : dd - 0.5f;
            dd = fabsf(lp.y - g1); acc += (dd < 1.0f) ? 0.5f * dd * dd : dd - 0.5f;
            dd = fabsf(lp.z - g2); acc += (dd < 1.0f) ? 0.5f * dd * dd : dd - 0.5f;
            dd = fabsf(lp.w - g3); acc += (dd < 1.0f) ? 0.5f * dd * dd : dd - 0.5f;
        }
    }
    sred[t] = acc; sredi[t] = cnt;
    __syncthreads();
    for (int s = 128; s > 0; s >>= 1) {
        if (t < s) { sred[t] += sred[t + s]; sredi[t] += sredi[t + s]; }
        __syncthreads();
    }
    if (t == 0) {
        if (sredi[0]) { atomicAdd(&n_pos[b], sredi[0]); atomicAdd(npt, sredi[0]); }
        if (sred[0] != 0.0) atomicAdd(loc_sum, sred[0]);
    }
}

// ---------------------------------------------------------------------------
// ce (fast path): 64-row LDS tiles, 4 threads/row, registers, hw transcend.
// ---------------------------------------------------------------------------
template<int CC>
__global__ __launch_bounds__(256) void ce_tile_kernel(
        const float* __restrict__ cls, const int* __restrict__ tcls,
        float* __restrict__ negbuf, double* __restrict__ pos_sum, int R) {
    constexpr int TF  = 64 * CC;
    constexpr int TF4 = TF / 4;
    constexpr int PER = (CC + 3) / 4;
    __shared__ __align__(16) float lds[TF];
    int t = threadIdx.x;
    int ntiles = R / 64;
    double acc = 0.0;

    for (int tile = blockIdx.x; tile < ntiles; tile += gridDim.x) {
        const float4* g4 = (const float4*)cls + (size_t)tile * TF4;
#pragma unroll
        for (int i = 0; i < (TF4 + 255) / 256; ++i) {
            int idx = t + i * 256;
            if (idx < TF4) ((float4*)lds)[idx] = g4[idx];
        }
        __syncthreads();

        int rr = t >> 2, p = t & 3;
        int row = tile * 64 + rr;
        const float* Lr = lds + rr * CC;
        int j0 = p * PER;

        float v[PER];
#pragma unroll
        for (int k = 0; k < PER; ++k) {
            int j = j0 + k;
            v[k] = (j < CC) ? Lr[j] : -INFINITY;
        }
        float m = v[0];
#pragma unroll
        for (int k = 1; k < PER; ++k) m = fmaxf(m, v[k]);
        m = fmaxf(m, __shfl_xor(m, 1));
        m = fmaxf(m, __shfl_xor(m, 2));
        float e = 0.0f;
#pragma unroll
        for (int k = 0; k < PER; ++k) e += __expf(v[k] - m);
        e += __shfl_xor(e, 1);
        e += __shfl_xor(e, 2);

        if (p == 0) {
            int tgt = tcls[row];
            float lt = Lr[tgt];
            float ce = fmaxf(__logf(e) + m - lt, 0.0f);
            if (tgt != 0) acc += (double)ce;
            negbuf[row] = (tgt != 0) ? 0.0f : ce;
        }
        __syncthreads();
    }

    double* sd = (double*)lds;
    sd[t] = acc;
    __syncthreads();
    for (int s = 128; s > 0; s >>= 1) {
        if (t < s) sd[t] += sd[t + s];
        __syncthreads();
    }
    if (t == 0 && sd[0] != 0.0) atomicAdd(pos_sum, sd[0]);
}

__global__ void ce_kernel(const float* __restrict__ cls, const int* __restrict__ tcls,
                          float* __restrict__ negbuf, double* __restrict__ pos_sum,
                          int R, int C) {
    int gid  = blockIdx.x * blockDim.x + threadIdx.x;
    int wid  = gid >> 6, lane = threadIdx.x & 63;
    int nw   = (gridDim.x * blockDim.x) >> 6;
    double acc = 0.0;
    for (int r = wid; r < R; r += nw) {
        const float* base = cls + (size_t)r * C;
        float m = -INFINITY;
        for (int i = lane; i < C; i += 64) m = fmaxf(m, base[i]);
        for (int s = 32; s > 0; s >>= 1) m = fmaxf(m, __shfl_xor(m, s));
        float e = 0.0f;
        for (int i = lane; i < C; i += 64) e += __expf(base[i] - m);
        for (int s = 32; s > 0; s >>= 1) e += __shfl_xor(e, s);
        int tgt = tcls[r];
        float ce = fmaxf(__logf(e) + m - base[tgt], 0.0f);
        if (lane == 0) {
            if (tgt != 0) { acc += (double)ce; negbuf[r] = 0.0f; }
            else          { negbuf[r] = ce; }
        }
    }
    if (lane == 0 && acc != 0.0) atomicAdd(pos_sum, acc);
}

// ---------------------------------------------------------------------------
// hardneg (+ fused finalize): exact top-k sum via byte radix-select.
// Pass 1 reads global and caches row in dynamic LDS; passes 2-4 read LDS.
// Count AND value-sum histograms fused -> no separate final sum pass.
// Last block to finish writes the two output scalars.
// ---------------------------------------------------------------------------
__global__ __launch_bounds__(256) void hardneg_kernel(
        const float* __restrict__ neg, const int* __restrict__ n_pos,
        double* __restrict__ neg_sum, const int* __restrict__ npt,
        const double* __restrict__ loc_sum, const double* __restrict__ pos_sum,
        int* __restrict__ counter, float* __restrict__ out,
        int D, int uselds) {
    extern __shared__ float ldsrow[];               // D floats (if uselds)
    int b = blockIdx.x, t = threadIdx.x;
    int w = t >> 6;
    const float* row = neg + (size_t)b * D;

    __shared__ unsigned bins[4][256];
    __shared__ float    fbins[4][256];
    __shared__ unsigned sh_kk, sh_prefix, sh_pmask;
    __shared__ double   sh_above;

    int k0 = 3 * n_pos[b];
    if (k0 > D) k0 = D;
    if (t == 0) { sh_kk = (unsigned)k0; sh_prefix = 0u; sh_pmask = 0u; sh_above = 0.0; }
    __syncthreads();

    if (k0 > 0) {
        for (int shift = 24; shift >= 0; shift -= 8) {
#pragma unroll
            for (int i = 0; i < 4; ++i) { bins[i][t] = 0; fbins[i][t] = 0.0f; }
            __syncthreads();
            unsigned pmask = sh_pmask, prefix = sh_prefix;
            if (shift == 24) {                       // first pass: global -> LDS
                for (int i = t; i < D; i += 256) {
                    float fv = row[i];
                    if (uselds) ldsrow[i] = fv;
                    unsigned v = __float_as_uint(fv);
                    atomicAdd(&bins[w][v >> 24], 1u);
                    atomicAdd(&fbins[w][v >> 24], fv);
                }
            } else {
                for (int i = t; i < D; i += 256) {
                    float fv = uselds ? ldsrow[i] : row[i];
                    unsigned v = __float_as_uint(fv);
                    if ((v & pmask) == prefix) {
                        atomicAdd(&bins[w][(v >> shift) & 255u], 1u);
                        atomicAdd(&fbins[w][(v >> shift) & 255u], fv);
                    }
                }
            }
            __syncthreads();
            if (t == 0) {
                unsigned kk = sh_kk, cum = 0; int sel = 0;
                double above = 0.0;
                for (int bb = 255; bb >= 0; --bb) {
                    unsigned c = bins[0][bb] + bins[1][bb] + bins[2][bb] + bins[3][bb];
                    if (cum + c >= kk) { sel = bb; break; }
                    cum += c;
                    above += (double)(fbins[0][bb] + fbins[1][bb] +
                                      fbins[2][bb] + fbins[3][bb]);
                }
                sh_above += above;
                sh_kk = kk - cum;
                sh_prefix = prefix | ((unsigned)sel << shift);
                sh_pmask = pmask | (255u << shift);
            }
            __syncthreads();
        }
        if (t == 0) {
            double tot = sh_above +
                (double)sh_kk * (double)__uint_as_float(sh_prefix);
            if (tot != 0.0) atomicAdd(neg_sum, tot);
        }
    }

    // fused finalize: last block writes outputs
    __threadfence();
    if (t == 0) {
        int done = atomicAdd(counter, 1);
        if (done == (int)gridDim.x - 1) {
            double ls = atomicAdd(loc_sum == NULL ? NULL : (double*)loc_sum, 0.0);
            double ps = atomicAdd((double*)pos_sum, 0.0);
            double ns = atomicAdd(neg_sum, 0.0);
            int    n  = atomicAdd((int*)npt, 0);
            double nd = (double)n;
            out[0] = (float)(ls / (nd * 4.0));
            out[1] = (float)((ns + ps) / nd);
        }
    }
}

// ---------------------------------------------------------------------------
extern "C" void kernel_launch(void* const* d_in, const int* in_sizes, int n_in,
                              void* d_out, int out_size, void* d_ws, size_t ws_size,
                              hipStream_t stream) {
    const float* locs   = (const float*)d_in[0];
    const float* cls    = (const float*)d_in[1];
    const float* boxes  = (const float*)d_in[2];
    const int*   labels = (const int*)d_in[3];
    const float* dboxes = (const float*)d_in[4];

    int D = in_sizes[4] / 4;
    int B = in_sizes[0] / (4 * D);
    int O = in_sizes[3] / B;
    int C = in_sizes[1] / (B * D);
    int R = B * D;

    const int chunk = 1024;
    int CH1 = (D + chunk - 1) / chunk;
    int CHm = (D + 255) / 256;

    char* ws = (char*)d_ws;
    double* loc_sum = (double*)ws;                    // [0,8)
    double* pos_sum = loc_sum + 1;                    // [8,16)
    double* neg_sum = loc_sum + 2;                    // [16,24)
    int*    npt     = (int*)(ws + 24);                // [24,28)
    int*    counter = (int*)(ws + 28);                // [28,32)
    size_t off = 32;
    int* n_pos = (int*)(ws + off); off += (size_t)B * 4;
    int* dstar = (int*)(ws + off); off += (size_t)B * O * 4;
    off = (off + 7) & ~(size_t)7;
    unsigned long long* key64c = (unsigned long long*)(ws + off);
    off += (size_t)B * CH1 * O * 8;
    off = (off + 15) & ~(size_t)15;
    int*   tcls   = (int*)(ws + off); off += (size_t)R * 4;
    float* negbuf = (float*)(ws + off);

    m1_kernel<<<B * CH1, 256, 0, stream>>>(boxes, dboxes, tcls, negbuf /*ovl*/,
                                           key64c, n_pos, loc_sum, pos_sum, neg_sum,
                                           npt, counter, D, O, CH1, chunk);
    m2r_kernel<<<1, 256, 0, stream>>>(key64c, dstar, B, O, CH1);
    m3_kernel<<<B * CHm, 256, 0, stream>>>(boxes, labels, dboxes, locs, tcls, negbuf,
                                           dstar, n_pos, loc_sum, npt, D, O, CHm);
    if (C == 81 && (R % 64) == 0) {
        int ntiles = R / 64;
        int grid = ntiles < 1792 ? ntiles : 1792;
        ce_tile_kernel<81><<<grid, 256, 0, stream>>>(cls, tcls, negbuf, pos_sum, R);
    } else {
        ce_kernel<<<2048, 256, 0, stream>>>(cls, tcls, negbuf, pos_sum, R, C);
    }
    int uselds = (D * 4 <= 60000) ? 1 : 0;
    size_t shbytes = uselds ? (size_t)D * 4 : 0;
    hardneg_kernel<<<B, 256, shbytes, stream>>>(negbuf, n_pos, neg_sum, npt,
                                                loc_sum, pos_sum, counter,
                                                (float*)d_out, D, uselds);
}